// Round 6
// baseline (138.426 us; speedup 1.0000x reference)
//
#include <hip/hip_runtime.h>
#include <hip/hip_bf16.h>

namespace {

constexpr int Bb = 2, Hh = 32, HKVc = 8, Tt = 2048, Dd = 128;
constexpr float LOG2E = 1.44269504088896340736f;

typedef float  f32x4  __attribute__((ext_vector_type(4)));
typedef float  f32x16 __attribute__((ext_vector_type(16)));
typedef short  bf16x8 __attribute__((ext_vector_type(8)));
typedef unsigned int u32;
typedef u32    u32x2  __attribute__((ext_vector_type(2)));
typedef u32    u32x4  __attribute__((ext_vector_type(4)));

__device__ inline u32 cvtpk(float a, float b) {  // [bf16(a) lo | bf16(b) hi]
  u32 r;
  asm("v_cvt_pk_bf16_f32 %0, %1, %2" : "=v"(r) : "v"(a), "v"(b));
  return r;
}

// (x,y) -> x' = [x_lo, y_lo], y' = [x_hi, y_hi]  (swap upper32(x) with lower32(y))
__device__ inline void pl32swap(u32& x, u32& y) {
#if __has_builtin(__builtin_amdgcn_permlane32_swap)
  auto r = __builtin_amdgcn_permlane32_swap(x, y, false, false);
  x = r[0]; y = r[1];
#else
  asm("v_permlane32_swap_b32 %0, %1" : "+v"(x), "+v"(y));
#endif
}

__device__ inline void gload_lds16(const void* g, void* l) {
  __builtin_amdgcn_global_load_lds((const __attribute__((address_space(1))) unsigned int*)g,
                                   (__attribute__((address_space(3))) unsigned int*)l, 16, 0, 0);
}

// ---------------- pre-pass: fp32 K/V -> bf16 swizzled tile images in ws ----------------
// K tile image (8192B): 16B chunk (row,c'): K[row][8*(c'^(row&7)) .. +8),  row=kv 0..31, c' 0..15
// V tile image (8192B): 16B chunk (row,c'): c=c'^(row&7); d=2*row+(c>>2); kv0=8*(c&3);
//                       holds pairs (V[kv0+2w][d],V[kv0+2w+1][d]) w=0..3
__global__ __launch_bounds__(256) void prep_kernel(const float* __restrict__ K,
                                                   const float* __restrict__ V,
                                                   short* __restrict__ Kb, short* __restrict__ Vb) {
  __shared__ float Vlds[32][132];
  const int blk = blockIdx.x;              // (b*HKV+hkv)*64 + tile
  const int tid = threadIdx.x;
  const float* ksrc = K + (size_t)blk * 32 * Dd;
  const float* vsrc = V + (size_t)blk * 32 * Dd;
  short* kdst = Kb + (size_t)blk * 4096;
  short* vdst = Vb + (size_t)blk * 4096;

#pragma unroll
  for (int i = 0; i < 2; ++i) {            // K: 512 chunks / 256 threads
    int idx = tid + i * 256;
    int row = idx >> 4, c = idx & 15;
    int d0 = 8 * (c ^ (row & 7));
    f32x4 a = *(const f32x4*)(ksrc + row * Dd + d0);
    f32x4 b = *(const f32x4*)(ksrc + row * Dd + d0 + 4);
    u32x4 ov;
    ov[0] = cvtpk(a[0], a[1]); ov[1] = cvtpk(a[2], a[3]);
    ov[2] = cvtpk(b[0], b[1]); ov[3] = cvtpk(b[2], b[3]);
    *(u32x4*)(kdst + (size_t)idx * 8) = ov;
  }
#pragma unroll
  for (int i = 0; i < 4; ++i) {            // V: coalesced fp32 -> LDS
    int idx = tid + i * 256;
    int row = idx >> 5, c4 = idx & 31;
    *(f32x4*)&Vlds[row][c4 * 4] = *(const f32x4*)(vsrc + row * Dd + c4 * 4);
  }
  __syncthreads();
#pragma unroll
  for (int i = 0; i < 2; ++i) {            // V image: pair-packed transposed chunks
    int idx = tid + i * 256;
    int row = idx >> 3, cp = idx & 7;
    int c = cp ^ (row & 7);
    int d = 2 * row + (c >> 2);
    int kv0 = 8 * (c & 3);
    u32x4 ov;
    ov[0] = cvtpk(Vlds[kv0 + 0][d], Vlds[kv0 + 1][d]);
    ov[1] = cvtpk(Vlds[kv0 + 2][d], Vlds[kv0 + 3][d]);
    ov[2] = cvtpk(Vlds[kv0 + 4][d], Vlds[kv0 + 5][d]);
    ov[3] = cvtpk(Vlds[kv0 + 6][d], Vlds[kv0 + 7][d]);
    *(u32x4*)(vdst + (size_t)idx * 8) = ov;
  }
}

// ---------------- main: 1024 blocks x 4 waves, 32 q-rows/wave, S^T + in-register P ------
__global__ __launch_bounds__(256, 4) void fattn_main(const float* __restrict__ Q,
                                                     const short* __restrict__ Kb,
                                                     const short* __restrict__ Vb,
                                                     const float* __restrict__ scale_p,
                                                     float* __restrict__ O) {
  __shared__ short Klds[2 * 4096];         // 16 KB
  __shared__ short Vt[2 * 4096];           // 16 KB

  const int z = blockIdx.x;
  const int qb = 15 - (z >> 6);            // heavy-first (harmless if all resident)
  const int bh = z & 63;
  const int b = bh >> 5, h = bh & 31, hkv = h >> 2;

  const int tid = threadIdx.x;
  const int w = tid >> 6, lane = tid & 63;
  const int l31 = lane & 31, hh = lane >> 5;

  const float qsc = LOG2E / scale_p[0];
  const int qrow0 = qb * 128 + w * 32;
  const int nt = 4 * qb + 4;

  const short* ktiles = Kb + (size_t)(b * HKVc + hkv) * 64 * 4096;
  const short* vtiles = Vb + (size_t)(b * HKVc + hkv) * 64 * 4096;

  // Q frags: lane (l31,hh): A/B[row|col=l31][k=8hh+j], frag kk -> d = kk*16+8hh+j
  bf16x8 qf[8];
  {
    const float* qp = Q + ((size_t)(b * Hh + h) * Tt + qrow0 + l31) * Dd;
#pragma unroll
    for (int kk = 0; kk < 8; ++kk) {
      const float* p0 = qp + kk * 16 + hh * 8;
      f32x4 a = *(const f32x4*)(p0);
      f32x4 c = *(const f32x4*)(p0 + 4);
      u32* qd = (u32*)&qf[kk];
      qd[0] = cvtpk(a[0] * qsc, a[1] * qsc);
      qd[1] = cvtpk(a[2] * qsc, a[3] * qsc);
      qd[2] = cvtpk(c[0] * qsc, c[1] * qsc);
      qd[3] = cvtpk(c[2] * qsc, c[3] * qsc);
    }
  }

  f32x16 acc[4];
#pragma unroll
  for (int n = 0; n < 4; ++n)
#pragma unroll
    for (int i = 0; i < 16; ++i) acc[n][i] = 0.f;
  float lsum = 0.f;

  // XOR-folded LDS addresses
  const int swz = l31 & 7;
  const int kbyte = l31 * 256 + ((hh ^ swz) << 4);                       // ^ (kk<<5)
  const int vbyte = (l31 >> 1) * 128 +
                    ((((l31 & 1) << 2) ^ hh ^ ((l31 >> 1) & 7)) << 4);   // ^ (kf<<5), +n*2048

  // ---- prologue: stage tile 0 into half 0 ----
#pragma unroll
  for (int i = 0; i < 2; ++i) {
    gload_lds16(ktiles + (size_t)(tid + i * 256) * 8, &Klds[(w * 64 + i * 256) * 8]);
    gload_lds16(vtiles + (size_t)(tid + i * 256) * 8, &Vt[(w * 64 + i * 256) * 8]);
  }
  __syncthreads();

  for (int t = 0; t < nt; ++t) {
    const int cur = t & 1, nxt = cur ^ 1;
    if (t + 1 < nt) {
      const short* kt = ktiles + (size_t)(t + 1) * 4096;
      const short* vt = vtiles + (size_t)(t + 1) * 4096;
#pragma unroll
      for (int i = 0; i < 2; ++i) {
        gload_lds16(kt + (size_t)(tid + i * 256) * 8, &Klds[nxt * 4096 + (w * 64 + i * 256) * 8]);
        gload_lds16(vt + (size_t)(tid + i * 256) * 8, &Vt[nxt * 4096 + (w * 64 + i * 256) * 8]);
      }
    }

    const int col0 = t * 32;
    if (col0 <= qrow0 + 31) {              // wave-uniform activity
      const char* kb = (const char*)Klds + cur * 8192;
      const char* vb = (const char*)Vt + cur * 8192;

      // ---- S^T = K Q^T  (D[i=kv][j=q]: j=l31, i=(r&3)+8(r>>2)+4hh) ----
      f32x16 s;
#pragma unroll
      for (int i = 0; i < 16; ++i) s[i] = 0.f;
#pragma unroll
      for (int kk = 0; kk < 8; ++kk) {
        bf16x8 kf = *(const bf16x8*)(kb + (kbyte ^ (kk << 5)));
        s = __builtin_amdgcn_mfma_f32_32x32x16_bf16(kf, qf[kk], s, 0, 0, 0);
      }

      const bool dm = (col0 == qrow0);     // the single diagonal tile for this wave
      const int hh4 = 4 * hh;

#pragma unroll
      for (int kf2 = 0; kf2 < 2; ++kf2) {  // kv group 16*kf2 .. +15
        float p[8];
#pragma unroll
        for (int rr = 0; rr < 8; ++rr) {
          float pv = exp2f(s[kf2 * 8 + rr]);
          if (dm) {
            const int crow = (rr & 3) + 8 * (rr >> 2) + 16 * kf2;  // + hh4 runtime
            pv = (crow + hh4 > l31) ? 0.f : pv;   // mask kv > q
          }
          p[rr] = pv;
        }
        lsum += ((p[0] + p[1]) + (p[2] + p[3])) + ((p[4] + p[5]) + (p[6] + p[7]));

        // build PV A-fragment in registers: kv pairs -> words, cross-half via permlane
        u32 a0 = cvtpk(p[0], p[1]), a1 = cvtpk(p[2], p[3]);
        u32 a2 = cvtpk(p[4], p[5]), a3 = cvtpk(p[6], p[7]);
        pl32swap(a0, a2);                  // a0 -> W0 (kv 8hh..+1), a2 -> W2 (kv 4+8hh? -> per-deriv OK)
        pl32swap(a1, a3);                  // a1 -> W1, a3 -> W3
        bf16x8 pa;
        u32* pw = (u32*)&pa;
        pw[0] = a0; pw[1] = a1; pw[2] = a2; pw[3] = a3;

        const char* vk = vb + (vbyte ^ (kf2 << 5));
#pragma unroll
        for (int n = 0; n < 4; ++n) {
          bf16x8 vf = *(const bf16x8*)(vk + n * 2048);
          acc[n] = __builtin_amdgcn_mfma_f32_32x32x16_bf16(pa, vf, acc[n], 0, 0, 0);
        }
      }
    }
    __syncthreads();
  }

  // ---- epilogue: lsum lives per lane (q=l31, own hh-half kv slices) ----
  float ltot = lsum + __shfl_xor(lsum, 32);
  float* op = O + ((size_t)(b * Hh + h) * Tt + qrow0) * Dd;
#pragma unroll
  for (int r = 0; r < 16; ++r) {
    const int crow = (r & 3) + 8 * (r >> 2) + 4 * hh;   // output q row of acc reg r
    float lr = __shfl(ltot, crow);
    float inv = 1.0f / lr;
#pragma unroll
    for (int n = 0; n < 4; ++n)
      op[(size_t)crow * Dd + n * 32 + l31] = acc[n][r] * inv;
  }
}

// ---------------- fallback (R4 kernel, used only if ws too small) ----------------
constexpr int FBKV = 32, FNW = 8, FNQB = 16;
constexpr int FKLD = 136, FVLD = 40, FPLD = 40;
constexpr float MSC = 8.0f * LOG2E;

__global__ __launch_bounds__(512, 4) void fattn_fb(const float* __restrict__ Q,
                                                   const float* __restrict__ K,
                                                   const float* __restrict__ V,
                                                   const float* __restrict__ scale_p,
                                                   float* __restrict__ O) {
  __shared__ short Klds[2][FBKV * FKLD];
  __shared__ short Vt[2][Dd * FVLD];
  __shared__ short Plds[FNW * 16 * FPLD];
  const int pp = blockIdx.x >> 6;
  const int bh = blockIdx.x & 63;
  const int b = bh >> 5, h = bh & 31, hkv = h >> 2;
  const int tid = threadIdx.x;
  const int w = tid >> 6, lane = tid & 63, l15 = lane & 15, g = lane >> 4;
  const float qsc = LOG2E / scale_p[0];
  const float* kbase = K + (size_t)(b * HKVc + hkv) * Tt * Dd;
  const float* vbase = V + (size_t)(b * HKVc + hkv) * Tt * Dd;
  const int krow = tid >> 5, kc4 = tid & 31;
  const int vc = tid & 31, kv0 = 2 * (tid >> 5);
  short* Pw = Plds + w * 16 * FPLD;
#pragma unroll 1
  for (int seg = 0; seg < 2; ++seg) {
    const int qb = (seg == 0) ? (FNQB - 1 - pp) : pp;
    const int qrow0 = qb * 128 + w * 16;
    const int nt = 4 * qb + 4;
    bf16x8 qf[4];
    {
      const float* qp = Q + ((size_t)(b * Hh + h) * Tt + qrow0 + l15) * Dd;
#pragma unroll
      for (int kk = 0; kk < 4; ++kk) {
        f32x4 a = *(const f32x4*)(qp + kk * 32 + g * 8);
        f32x4 c = *(const f32x4*)(qp + kk * 32 + g * 8 + 4);
        u32* qd = (u32*)&qf[kk];
        qd[0] = cvtpk(a[0] * qsc, a[1] * qsc); qd[1] = cvtpk(a[2] * qsc, a[3] * qsc);
        qd[2] = cvtpk(c[0] * qsc, c[1] * qsc); qd[3] = cvtpk(c[2] * qsc, c[3] * qsc);
      }
    }
    f32x4 acc[8];
#pragma unroll
    for (int n = 0; n < 8; ++n) { acc[n][0]=0.f; acc[n][1]=0.f; acc[n][2]=0.f; acc[n][3]=0.f; }
    f32x4 accl; accl[0]=0.f; accl[1]=0.f; accl[2]=0.f; accl[3]=0.f;
    bf16x8 ones;
#pragma unroll
    for (int i = 0; i < 8; ++i) ones[i] = (short)0x3F80;
    {
      f32x4 k0 = *(const f32x4*)(kbase + (size_t)krow * Dd + kc4 * 4);
      f32x4 k1 = *(const f32x4*)(kbase + (size_t)(krow + 16) * Dd + kc4 * 4);
      float vr[8];
#pragma unroll
      for (int j = 0; j < 4; ++j) {
        vr[2*j]   = vbase[(size_t)kv0 * Dd + vc + 32 * j];
        vr[2*j+1] = vbase[(size_t)(kv0+1) * Dd + vc + 32 * j];
      }
      u32x2 kp;
      kp[0] = cvtpk(k0[0], k0[1]); kp[1] = cvtpk(k0[2], k0[3]);
      *(u32x2*)&Klds[0][krow * FKLD + kc4 * 4] = kp;
      kp[0] = cvtpk(k1[0], k1[1]); kp[1] = cvtpk(k1[2], k1[3]);
      *(u32x2*)&Klds[0][(krow + 16) * FKLD + kc4 * 4] = kp;
#pragma unroll
      for (int j = 0; j < 4; ++j)
        *(u32*)&Vt[0][(vc + 32 * j) * FVLD + kv0] = cvtpk(vr[2*j], vr[2*j+1]);
    }
    __syncthreads();
    for (int t = 0; t < nt; ++t) {
      const int cur = t & 1, nxt = cur ^ 1;
      const bool more = (t + 1 < nt);
      f32x4 kr0, kr1; float vr[8];
      if (more) {
        const float* ks = kbase + (size_t)(t + 1) * FBKV * Dd;
        const float* vs = vbase + (size_t)(t + 1) * FBKV * Dd;
        kr0 = *(const f32x4*)(ks + (size_t)krow * Dd + kc4 * 4);
        kr1 = *(const f32x4*)(ks + (size_t)(krow + 16) * Dd + kc4 * 4);
#pragma unroll
        for (int j = 0; j < 4; ++j) {
          vr[2*j]   = vs[(size_t)kv0 * Dd + vc + 32 * j];
          vr[2*j+1] = vs[(size_t)(kv0+1) * Dd + vc + 32 * j];
        }
      }
      const int col0 = t * FBKV;
      if (col0 <= qrow0 + 15) {
        f32x4 s0{}, s1{};
#pragma unroll
        for (int kk = 0; kk < 4; ++kk) {
          bf16x8 k0 = *(const bf16x8*)&Klds[cur][l15 * FKLD + kk * 32 + g * 8];
          bf16x8 k1 = *(const bf16x8*)&Klds[cur][(16 + l15) * FKLD + kk * 32 + g * 8];
          s0 = __builtin_amdgcn_mfma_f32_16x16x32_bf16(qf[kk], k0, s0, 0, 0, 0);
          s1 = __builtin_amdgcn_mfma_f32_16x16x32_bf16(qf[kk], k1, s1, 0, 0, 0);
        }
        const bool needm = (col0 + 31 > qrow0);
#pragma unroll
        for (int r = 0; r < 4; ++r) {
          const int qr = qrow0 + 4 * g + r;
          float p0 = exp2f(s0[r] - MSC);
          float p1 = exp2f(s1[r] - MSC);
          if (needm) {
            if (col0 + l15 > qr)      p0 = 0.f;
            if (col0 + 16 + l15 > qr) p1 = 0.f;
          }
          u32 pk = cvtpk(p0, p1);
          Pw[(4 * g + r) * FPLD + l15]      = (short)(pk & 0xffffu);
          Pw[(4 * g + r) * FPLD + 16 + l15] = (short)(pk >> 16);
        }
        bf16x8 pa = *(const bf16x8*)&Pw[l15 * FPLD + g * 8];
        accl = __builtin_amdgcn_mfma_f32_16x16x32_bf16(pa, ones, accl, 0, 0, 0);
#pragma unroll
        for (int n = 0; n < 8; ++n) {
          bf16x8 vf = *(const bf16x8*)&Vt[cur][(n * 16 + l15) * FVLD + g * 8];
          acc[n] = __builtin_amdgcn_mfma_f32_16x16x32_bf16(pa, vf, acc[n], 0, 0, 0);
        }
      }
      if (more) {
        u32x2 kp;
        kp[0] = cvtpk(kr0[0], kr0[1]); kp[1] = cvtpk(kr0[2], kr0[3]);
        *(u32x2*)&Klds[nxt][krow * FKLD + kc4 * 4] = kp;
        kp[0] = cvtpk(kr1[0], kr1[1]); kp[1] = cvtpk(kr1[2], kr1[3]);
        *(u32x2*)&Klds[nxt][(krow + 16) * FKLD + kc4 * 4] = kp;
#pragma unroll
        for (int j = 0; j < 4; ++j)
          *(u32*)&Vt[nxt][(vc + 32 * j) * FVLD + kv0] = cvtpk(vr[2*j], vr[2*j+1]);
      }
      __syncthreads();
    }
    float* op = O + ((size_t)(b * Hh + h) * Tt + qrow0) * Dd;
#pragma unroll
    for (int r = 0; r < 4; ++r) {
      float inv_l = 1.0f / accl[r];
#pragma unroll
      for (int n = 0; n < 8; ++n)
        op[(size_t)(4 * g + r) * Dd + n * 16 + l15] = acc[n][r] * inv_l;
    }
    __syncthreads();
  }
}

}  // namespace

extern "C" void kernel_launch(void* const* d_in, const int* in_sizes, int n_in,
                              void* d_out, int out_size, void* d_ws, size_t ws_size,
                              hipStream_t stream) {
  const float* Q = (const float*)d_in[0];
  const float* K = (const float*)d_in[1];
  const float* V = (const float*)d_in[2];
  const float* s = (const float*)d_in[3];
  float* O = (float*)d_out;
  const size_t ntile = (size_t)Bb * HKVc * (Tt / 32);          // 1024 tiles
  const size_t need = 2 * ntile * 4096 * sizeof(short);        // 16.78 MB
  if (ws_size >= need) {
    short* Kb = (short*)d_ws;
    short* Vb = Kb + ntile * 4096;
    prep_kernel<<<dim3((unsigned)ntile), 256, 0, stream>>>(K, V, Kb, Vb);
    fattn_main<<<dim3(16 * Bb * Hh), 256, 0, stream>>>(Q, Kb, Vb, s, O);
  } else {
    fattn_fb<<<dim3(8 * Bb * Hh), 512, 0, stream>>>(Q, K, V, s, O);
  }
}